// Round 11
// baseline (570.305 us; speedup 1.0000x reference)
//
#include <hip/hip_runtime.h>
#include <hip/hip_bf16.h>
#include <stdint.h>

// ---------------------------------------------------------------------------
// MultiHeadSeqAttention (Transformer-XL style sliding-window rel-pos attention)
// HID=1024, NHEADS=16, HEAD=64, MEM=512, LIM=2048, B=8
// logit(m,n) = q[m]·k[n] + q[m]·pe[:,n-m],  n-m in [0,2048)
// ---------------------------------------------------------------------------

typedef __attribute__((ext_vector_type(8))) __bf16 bfrag;   // MFMA A/B operand
typedef __attribute__((ext_vector_type(4))) float f4;       // MFMA C/D
typedef __attribute__((ext_vector_type(4))) unsigned int u32x4;

#define DEVFN static __device__ __forceinline__

DEVFN void glds16(const void* g, void* l) {
  __builtin_amdgcn_global_load_lds((const __attribute__((address_space(1))) void*)g,
                                   (__attribute__((address_space(3))) void*)l, 16, 0, 0);
}

DEVFN bfrag cvt8(const float* p) {
  f4 a = *(const f4*)p;
  f4 b = *(const f4*)(p + 4);
  bfrag v;
  v[0] = (__bf16)a.x; v[1] = (__bf16)a.y; v[2] = (__bf16)a.z; v[3] = (__bf16)a.w;
  v[4] = (__bf16)b.x; v[5] = (__bf16)b.y; v[6] = (__bf16)b.z; v[7] = (__bf16)b.w;
  return v;
}

DEVFN uint32_t cvtpk(float lo, float hi) {
  uint32_t r;
  asm("v_cvt_pk_bf16_f32 %0, %1, %2" : "=v"(r) : "v"(lo), "v"(hi));
  return r;
}

DEVFN uint32_t bperm(int addr, uint32_t v) {
  return (uint32_t)__builtin_amdgcn_ds_bpermute(addr, (int)v);
}

DEVFN bfrag as_bfrag(uint32_t a, uint32_t b, uint32_t c, uint32_t d) {
  u32x4 t = {a, b, c, d};
  return __builtin_bit_cast(bfrag, t);
}

// ------------------ fp32 -> bf16 convert, 4 weights in one launch ----------
__global__ __launch_bounds__(256) void conv4(const float* __restrict__ a0, const float* __restrict__ a1,
                                             const float* __restrict__ a2, const float* __restrict__ a3,
                                             __bf16* __restrict__ d0, __bf16* __restrict__ d1,
                                             __bf16* __restrict__ d2, __bf16* __restrict__ d3) {
  int bx = blockIdx.x;
  int sel = bx >> 9;
  const float* s = sel == 0 ? a0 : sel == 1 ? a1 : sel == 2 ? a2 : a3;
  __bf16* d = sel == 0 ? d0 : sel == 1 ? d1 : sel == 2 ? d2 : d3;
  int i = ((bx & 511) * 256 + (int)threadIdx.x) * 8;   // 512*256*8 = 1M exactly
  *(bfrag*)(d + i) = cvt8(s + i);
}

// ------------------ fp32 -> bf16 convert for q/k/v inputs ------------------
__global__ __launch_bounds__(256) void convin(const float* __restrict__ q, const float* __restrict__ k,
                                              const float* __restrict__ v,
                                              __bf16* __restrict__ qd, __bf16* __restrict__ kd,
                                              __bf16* __restrict__ vd) {
  int bx = blockIdx.x;
  const float* s; __bf16* d; int lb;
  if (bx < 2048)       { s = q; d = qd; lb = bx; }
  else if (bx < 12288) { s = k; d = kd; lb = bx - 2048; }
  else                 { s = v; d = vd; lb = bx - 12288; }
  int i = (lb * 256 + (int)threadIdx.x) * 8;
  *(bfrag*)(d + i) = cvt8(s + i);
}

// ---------------- transposed + zero-padded positional table ----------------
__global__ __launch_bounds__(256) void pek(const float* __restrict__ pe,
                                           __bf16* __restrict__ peT) {
  int i = blockIdx.x * 256 + threadIdx.x;   // grid covers 64*2048 + 128*64 exactly
  if (i < 64 * 2048) {
    int d = i >> 11, l = i & 2047;
    peT[(size_t)(l + 64) * 64 + d] = (__bf16)pe[i];
  } else {
    int zi = i - 64 * 2048;
    int row = zi >> 6, dd = zi & 63;
    int r = row < 64 ? row : (2112 + row - 64);
    peT[(size_t)r * 64 + dd] = (__bf16)0.f;
  }
}

// ---------------------------------------------------------------------------
// core16: 128x128 tile, BK=64, 16 K-steps, counted-vmcnt pipeline (R5 win).
// ---------------------------------------------------------------------------
DEVFN bfrag rdfrag(const __bf16* L, int row, int kc, int g) {
  return *(const bfrag*)&L[row * 64 + (((g + 4 * kc) ^ (row & 7)) << 3)];
}

DEVFN void core16(const __bf16* __restrict__ A, const __bf16* __restrict__ B,
                  __bf16* AL, __bf16* BL, f4 (&acc)[4][4],
                  int tid, int wr, int wc, int g, int cl) {
  auto stageA = [&](int s, int k0) {
#pragma unroll
    for (int j = 0; j < 4; ++j) {
      int slot = j * 256 + tid;
      int row = slot >> 3, ch = slot & 7;
      glds16(A + (size_t)row * 1024 + k0 + ((ch ^ (row & 7)) << 3),
             &AL[s * 8192 + (slot << 3)]);
    }
  };
  auto stageB = [&](int k0) {
#pragma unroll
    for (int j = 0; j < 4; ++j) {
      int slot = j * 256 + tid;
      int row = slot >> 3, ch = slot & 7;
      glds16(B + (size_t)row * 1024 + k0 + ((ch ^ (row & 7)) << 3),
             &BL[slot << 3]);
    }
  };

  stageA(0, 0);
  for (int kt = 0; kt < 16; ++kt) {
    const int s = kt & 1;
    stageB(kt * 64);
    if (kt < 15) {
      stageA(s ^ 1, (kt + 1) * 64);
      asm volatile("s_waitcnt vmcnt(4)" ::: "memory");
    } else {
      asm volatile("s_waitcnt vmcnt(0)" ::: "memory");
    }
    __builtin_amdgcn_s_barrier();
    const __bf16* As = &AL[s * 8192];
#pragma unroll
    for (int kc = 0; kc < 2; ++kc) {
      bfrag af[4], bf[4];
#pragma unroll
      for (int i = 0; i < 4; ++i) {
        af[i] = rdfrag(As, 64 * wr + 16 * i + cl, kc, g);
        bf[i] = rdfrag(BL, 64 * wc + 16 * i + cl, kc, g);
      }
      __builtin_amdgcn_s_setprio(1);
#pragma unroll
      for (int am = 0; am < 4; ++am)
#pragma unroll
        for (int bn = 0; bn < 4; ++bn)
          acc[am][bn] =
              __builtin_amdgcn_mfma_f32_16x16x32_bf16(af[am], bf[bn], acc[am][bn], 0, 0, 0);
      __builtin_amdgcn_s_setprio(0);
    }
    __builtin_amdgcn_s_barrier();
  }
}

// ---------------- fused q/k/v projection: C = A @ W^T, heads layout --------
__global__ __launch_bounds__(256) void projk_c(const __bf16* __restrict__ Aq, const __bf16* __restrict__ Ak,
                                               const __bf16* __restrict__ Av,
                                               const __bf16* __restrict__ Wqb, const __bf16* __restrict__ Wkb,
                                               const __bf16* __restrict__ Wvb,
                                               __bf16* __restrict__ qws, __bf16* __restrict__ kws,
                                               __bf16* __restrict__ vtws) {
  __shared__ alignas(16) __bf16 AL[2 * 128 * 64];   // 32 KiB (A dbuf)
  __shared__ alignas(16) __bf16 BL[128 * 64];       // 16 KiB (B single)
  int bx = blockIdx.x;
  const __bf16* A; const __bf16* B; __bf16* C; int nb, lb, rpb, trans;
  if (bx < 256)       { A = Aq; B = Wqb; C = qws;  lb = bx;        nb = 256;  rpb = 4;  trans = 0; }
  else if (bx < 1536) { A = Ak; B = Wkb; C = kws;  lb = bx - 256;  nb = 1280; rpb = 20; trans = 0; }
  else                { A = Av; B = Wvb; C = vtws; lb = bx - 1536; nb = 1280; rpb = 20; trans = 1; }

  const int tid = threadIdx.x;
  const int lane = tid & 63, wv = tid >> 6;
  const int wr = wv >> 1, wc = wv & 1;
  const int g = lane >> 4, cl = lane & 15;

  int v = (lb & 7) * (nb >> 3) + (lb >> 3);   // XCD-aware swizzle (nb % 8 == 0)
  const int trow = v >> 3;
  const int r0 = trow * 128, c0 = (v & 7) * 128;

  f4 acc[4][4] = {};
  core16(A + (size_t)r0 * 1024, B + (size_t)c0 * 1024, AL, BL, acc,
         tid, wr, wc, g, cl);

  int Sseq = rpb << 7;
  int b = trow / rpb;
  int sbase = r0 - b * Sseq;
#pragma unroll
  for (int am = 0; am < 4; ++am)
#pragma unroll
    for (int bn = 0; bn < 4; ++bn) {
      int jg = c0 + 64 * wc + 16 * bn + cl;
      int h = jg >> 6, d = jg & 63;
#pragma unroll
      for (int r = 0; r < 4; ++r) {
        int s = sbase + 64 * wr + 16 * am + 4 * g + r;
        size_t dst = trans ? ((size_t)(b * 16 + h) * 64 + d) * 2560 + s
                           : ((size_t)(b * 16 + h) * Sseq + s) * 64 + d;
        C[dst] = (__bf16)acc[am][bn][r];
      }
    }
}

// ------------------------- fp32 A reg-staging (fallback) -------------------
DEVFN void stageA_row(const float* ap, __bf16* lds, int arow, int ahalf) {
  const f4* p = (const f4*)ap;
#pragma unroll
  for (int q = 0; q < 4; ++q) {
    f4 a = p[2 * q], b = p[2 * q + 1];
    bfrag v;
    v[0] = (__bf16)a.x; v[1] = (__bf16)a.y; v[2] = (__bf16)a.z; v[3] = (__bf16)a.w;
    v[4] = (__bf16)b.x; v[5] = (__bf16)b.y; v[6] = (__bf16)b.z; v[7] = (__bf16)b.w;
    int ch = (4 * ahalf + q) ^ (arow & 7);
    *(bfrag*)&lds[arow * 64 + ch * 8] = v;
  }
}

// ---------------- fallback fused q/k/v projection (fp32 A) -----------------
__global__ __launch_bounds__(256) void projk_f32(const float* __restrict__ Aq, const float* __restrict__ Ak,
                                                 const float* __restrict__ Av,
                                                 const __bf16* __restrict__ Wqb, const __bf16* __restrict__ Wkb,
                                                 const __bf16* __restrict__ Wvb,
                                                 __bf16* __restrict__ qws, __bf16* __restrict__ kws,
                                                 __bf16* __restrict__ vtws) {
  __shared__ alignas(16) __bf16 Alds[128 * 64];
  __shared__ alignas(16) __bf16 Blds[128 * 64];
  int bx = blockIdx.x;
  const float* A; const __bf16* B; __bf16* C; int nb, lb, rpb, trans;
  if (bx < 256)       { A = Aq; B = Wqb; C = qws;  lb = bx;        nb = 256;  rpb = 4;  trans = 0; }
  else if (bx < 1536) { A = Ak; B = Wkb; C = kws;  lb = bx - 256;  nb = 1280; rpb = 20; trans = 0; }
  else                { A = Av; B = Wvb; C = vtws; lb = bx - 1536; nb = 1280; rpb = 20; trans = 1; }

  const int tid = threadIdx.x;
  const int lane = tid & 63, wv = tid >> 6;
  const int wr = wv >> 1, wc = wv & 1;
  const int g = lane >> 4, cl = lane & 15;

  int v = (lb & 7) * (nb >> 3) + (lb >> 3);
  const int trow = v >> 3;
  const int r0 = trow * 128, c0 = (v & 7) * 128;

  f4 acc[4][4] = {};

  for (int k0 = 0; k0 < 1024; k0 += 64) {
    __syncthreads();
#pragma unroll
    for (int i = 0; i < 4; ++i) {
      int slot = tid + 256 * i;
      int row = slot >> 3, ch = slot & 7;
      glds16(B + (size_t)(c0 + row) * 1024 + k0 + ((ch ^ (row & 7)) << 3),
             &Blds[slot << 3]);
    }
    stageA_row(A + (size_t)(r0 + (tid >> 1)) * 1024 + k0 + (tid & 1) * 32,
               Alds, tid >> 1, tid & 1);
    __syncthreads();
#pragma unroll
    for (int kc = 0; kc < 2; ++kc) {
      bfrag af[4], bfv[4];
#pragma unroll
      for (int i = 0; i < 4; ++i) {
        int rA = 64 * wr + 16 * i + cl;
        af[i] = *(const bfrag*)&Alds[rA * 64 + (((g + 4 * kc) ^ (rA & 7)) << 3)];
        int rB = 64 * wc + 16 * i + cl;
        bfv[i] = *(const bfrag*)&Blds[rB * 64 + (((g + 4 * kc) ^ (rB & 7)) << 3)];
      }
#pragma unroll
      for (int am = 0; am < 4; ++am)
#pragma unroll
        for (int bn = 0; bn < 4; ++bn)
          acc[am][bn] =
              __builtin_amdgcn_mfma_f32_16x16x32_bf16(af[am], bfv[bn], acc[am][bn], 0, 0, 0);
    }
  }

  int Sseq = rpb << 7;
  int b = trow / rpb;
  int sbase = r0 - b * Sseq;
#pragma unroll
  for (int am = 0; am < 4; ++am)
#pragma unroll
    for (int bn = 0; bn < 4; ++bn) {
      int jg = c0 + 64 * wc + 16 * bn + cl;
      int h = jg >> 6, d = jg & 63;
#pragma unroll
      for (int r = 0; r < 4; ++r) {
        int s = sbase + 64 * wr + 16 * am + 4 * g + r;
        size_t dst = trans ? ((size_t)(b * 16 + h) * 64 + d) * 2560 + s
                           : ((size_t)(b * 16 + h) * Sseq + s) * 64 + d;
        C[dst] = (__bf16)acc[am][bn][r];
      }
    }
}

// -------------------------- output projection (f32 out) --------------------
__global__ __launch_bounds__(256) void gemm_out(const __bf16* __restrict__ A,
                                                const __bf16* __restrict__ B,
                                                float* __restrict__ C) {
  __shared__ alignas(16) __bf16 AL[2 * 128 * 64];
  __shared__ alignas(16) __bf16 BL[128 * 64];
  const int tid = threadIdx.x;
  const int lane = tid & 63, wv = tid >> 6;
  const int wr = wv >> 1, wc = wv & 1;
  const int g = lane >> 4, cl = lane & 15;

  int bx = blockIdx.x;
  int v = (bx & 7) * 32 + (bx >> 3);
  const int r0 = (v >> 3) * 128, c0 = (v & 7) * 128;

  f4 acc[4][4] = {};
  core16(A + (size_t)r0 * 1024, B + (size_t)c0 * 1024, AL, BL, acc,
         tid, wr, wc, g, cl);

#pragma unroll
  for (int am = 0; am < 4; ++am)
#pragma unroll
    for (int bn = 0; bn < 4; ++bn)
#pragma unroll
      for (int r = 0; r < 4; ++r) {
        int rg = r0 + 64 * wr + 16 * am + 4 * g + r;
        int jg = c0 + 64 * wc + 16 * bn + cl;
        C[(size_t)rg * 1024 + jg] = acc[am][bn][r];
      }
}

// --------------------------- fused window attention ------------------------
// R11 = R10 with the ring hazard class removed:
//  (a) ring STORES are now plain __bf16 element stores (same type as the
//      loads) -> no type-punned u32/bf16 pair for TBAA to mis-order;
//  (b) write->read fence kept (lgkmcnt(0)+sched_barrier);
//  (c) end-of-iteration fence upgraded to lgkmcnt(0)+sched_barrier (R8's B2
//      semantics) so this iter's ring reads are HW-complete before next
//      iter's stores to the same mod-128 columns.
// Structure otherwise identical to R10: 1 wave/block, zero barriers, K/V/pe
// direct global->register (verified byte-equal to the LDS path's fragments).
#define SCL 0.18033688011112042f   // (1/8) * log2(e)
#define FMX 20.0f

__global__ __launch_bounds__(64, 3) void attnk(const __bf16* __restrict__ qws,
                                               const __bf16* __restrict__ kws,
                                               const __bf16* __restrict__ vtws,
                                               const __bf16* __restrict__ pews,
                                               __bf16* __restrict__ obuf) {
  __shared__ alignas(16) __bf16 ring[16 * 132];     // band: [q-local][l & 127]

  int bx = blockIdx.x;                              // 4096 = 128bh x 8mt x 4w
  int vv = (bx & 7) * 512 + (bx >> 3);              // XCD swizzle (bijective)
  int bh = vv >> 5, rem = vv & 31;
  int mt = rem >> 2, w = rem & 3;
  int m0 = mt * 64;                                 // this wave: q = m0+16w+0..15
  const __bf16* qb = qws + (size_t)bh * 512 * 64;
  const __bf16* kb = kws + (size_t)bh * 2560 * 64;
  const __bf16* vb = vtws + (size_t)bh * 64 * 2560;

  const int lane = (int)threadIdx.x & 63;
  const int g = lane >> 4, cl = lane & 15;

  // Q fragments: qf[kc] = Q[m0+16w+cl][8g+32kc .. +7]
  bfrag qf[2];
  {
    const __bf16* qrow = qb + (size_t)(m0 + 16 * w + cl) * 64 + 8 * g;
    qf[0] = *(const bfrag*)qrow;
    qf[1] = *(const bfrag*)(qrow + 32);
  }

  const int addrA = (32 * (g & 1) + cl) * 4;
  const int addrB = addrA + 64;
  const bool hi = (g >> 1) != 0;                    // lanes 32..63 take pk[2kc+1]
  const int rowoff = cl * 132;

  f4 o[4] = {};
  float lsum = 0.f;

  for (int t = 0; t < 33; ++t) {
    int n0 = m0 + 64 * t;

    // pe frags (consumed first), then K frags — counted waits free K to land
    bfrag pef[4][2], kfr[4][2];
    {
      const __bf16* peb = pews + (size_t)(64 + 64 * t + cl) * 64 + 8 * g;
#pragma unroll
      for (int lb = 0; lb < 4; ++lb) {
        pef[lb][0] = *(const bfrag*)(peb + (size_t)(16 * lb) * 64);
        pef[lb][1] = *(const bfrag*)(peb + (size_t)(16 * lb) * 64 + 32);
      }
      const __bf16* kbp = kb + (size_t)(n0 + cl) * 64 + 8 * g;
#pragma unroll
      for (int nb = 0; nb < 4; ++nb) {
        kfr[nb][0] = *(const bfrag*)(kbp + (size_t)(16 * nb) * 64);
        kfr[nb][1] = *(const bfrag*)(kbp + (size_t)(16 * nb) * 64 + 32);
      }
    }

    // band MFMAs; ring written as plain __bf16 stores (same type as loads)
#pragma unroll
    for (int lb = 0; lb < 4; ++lb) {
      f4 pbv = {};
      pbv = __builtin_amdgcn_mfma_f32_16x16x32_bf16(pef[lb][0], qf[0], pbv, 0, 0, 0);
      pbv = __builtin_amdgcn_mfma_f32_16x16x32_bf16(pef[lb][1], qf[1], pbv, 0, 0, 0);
      int colbase = (64 * t + 16 * lb + 4 * g) & 127;
#pragma unroll
      for (int j = 0; j < 4; ++j)
        ring[rowoff + colbase + j] = (__bf16)pbv[j];
    }
    // FENCE: ring stores HW-complete + no reordering of the following reads
    asm volatile("s_waitcnt lgkmcnt(0)" ::: "memory");
    __builtin_amdgcn_sched_barrier(0);

    // V^T frags issued here (pe regs dead -> allocator reuses; softmax covers)
    bfrag vfr[4][2];
#pragma unroll
    for (int db = 0; db < 4; ++db) {
      const __bf16* p = vb + (size_t)(16 * db + cl) * 2560 + n0 + 8 * g;
      vfr[db][0] = *(const bfrag*)p;
      vfr[db][1] = *(const bfrag*)(p + 32);
    }

    // content scores S^T
    f4 sc[4] = {};
    __builtin_amdgcn_s_setprio(1);
#pragma unroll
    for (int nb = 0; nb < 4; ++nb) {
      sc[nb] = __builtin_amdgcn_mfma_f32_16x16x32_bf16(kfr[nb][0], qf[0], sc[nb], 0, 0, 0);
      sc[nb] = __builtin_amdgcn_mfma_f32_16x16x32_bf16(kfr[nb][1], qf[1], sc[nb], 0, 0, 0);
    }
    __builtin_amdgcn_s_setprio(0);

    // fixed-max softmax, fully per-lane (q = 16w+cl)
    bool edge = (t == 0) | (t == 32);
    uint32_t pk[4][2];
    int l0 = 64 * t + 4 * g - cl - 16 * w;          // l = l0 + 16nb + r
#pragma unroll
    for (int nb = 0; nb < 4; ++nb) {
      float pv[4];
#pragma unroll
      for (int r = 0; r < 4; ++r) {
        int l = l0 + 16 * nb + r;
        float bnd = (float)ring[rowoff + (l & 127)];
        float ex = fmaf(sc[nb][r] + bnd, SCL, -FMX);
        if (edge) ex = ((unsigned)l < 2048u) ? ex : -1e30f;
        float pp = __builtin_amdgcn_exp2f(ex);
        lsum += pp;
        pv[r] = pp;
      }
      pk[nb][0] = cvtpk(pv[0], pv[1]);
      pk[nb][1] = cvtpk(pv[2], pv[3]);
    }

    // PV: assemble P A-frags via bpermute, multiply against V^T B-frags
    __builtin_amdgcn_s_setprio(1);
#pragma unroll
    for (int kc = 0; kc < 2; ++kc) {
      uint32_t t0, t1, u0, u1, u2, u3;
      t0 = bperm(addrA, pk[2 * kc][0]); t1 = bperm(addrA, pk[2 * kc + 1][0]);
      u0 = hi ? t1 : t0;
      t0 = bperm(addrA, pk[2 * kc][1]); t1 = bperm(addrA, pk[2 * kc + 1][1]);
      u1 = hi ? t1 : t0;
      t0 = bperm(addrB, pk[2 * kc][0]); t1 = bperm(addrB, pk[2 * kc + 1][0]);
      u2 = hi ? t1 : t0;
      t0 = bperm(addrB, pk[2 * kc][1]); t1 = bperm(addrB, pk[2 * kc + 1][1]);
      u3 = hi ? t1 : t0;
      bfrag pa = as_bfrag(u0, u1, u2, u3);
#pragma unroll
      for (int db = 0; db < 4; ++db)
        o[db] = __builtin_amdgcn_mfma_f32_16x16x32_bf16(pa, vfr[db][kc], o[db], 0, 0, 0);
    }
    __builtin_amdgcn_s_setprio(0);

    // FENCE: this iter's ring reads HW-complete before next iter's stores
    asm volatile("s_waitcnt lgkmcnt(0)" ::: "memory");
    __builtin_amdgcn_sched_barrier(0);
  }

  // epilogue: reduce lsum over the 4 g-lanes of each cl column, redistribute
  lsum += __shfl_xor(lsum, 16);
  lsum += __shfl_xor(lsum, 32);
  float rinv = 1.f / lsum;                          // valid for q = 16w+cl
  float rv[4];
#pragma unroll
  for (int r = 0; r < 4; ++r)
    rv[r] = __shfl(rinv, 4 * g + r);                // rinv for q = 16w+4g+r

  int b = bh >> 4, h = bh & 15;
#pragma unroll
  for (int db = 0; db < 4; ++db)
#pragma unroll
    for (int r = 0; r < 4; ++r) {
      int m = m0 + 16 * w + 4 * g + r;
      int d = 16 * db + cl;
      obuf[((size_t)(b * 512 + m)) * 1024 + h * 64 + d] = (__bf16)(o[db][r] * rv[r]);
    }
}

// ---------------------------------------------------------------------------
extern "C" void kernel_launch(void* const* d_in, const int* in_sizes, int n_in,
                              void* d_out, int out_size, void* d_ws, size_t ws_size,
                              hipStream_t stream) {
  const float* query = (const float*)d_in[0];
  const float* key   = (const float*)d_in[1];
  const float* value = (const float*)d_in[2];
  const float* keype = (const float*)d_in[3];
  const float* Wq    = (const float*)d_in[4];
  const float* Wk    = (const float*)d_in[5];
  const float* Wv    = (const float*)d_in[6];
  const float* Wo    = (const float*)d_in[7];
  float* out = (float*)d_out;
  (void)in_sizes; (void)n_in; (void)out_size;

  char* ws = (char*)d_ws;
  size_t off = 0;
  auto alloc = [&](size_t bytes) {
    void* p = ws + off;
    off += (bytes + 255) & ~(size_t)255;
    return p;
  };
  __bf16* Wqb  = (__bf16*)alloc((size_t)1024 * 1024 * 2);
  __bf16* Wkb  = (__bf16*)alloc((size_t)1024 * 1024 * 2);
  __bf16* Wvb  = (__bf16*)alloc((size_t)1024 * 1024 * 2);
  __bf16* Wob  = (__bf16*)alloc((size_t)1024 * 1024 * 2);
  __bf16* peT  = (__bf16*)alloc((size_t)2176 * 64 * 2);
  __bf16* qws  = (__bf16*)alloc((size_t)128 * 512 * 64 * 2);
  __bf16* kws  = (__bf16*)alloc((size_t)128 * 2560 * 64 * 2);
  __bf16* vtws = (__bf16*)alloc((size_t)128 * 2560 * 64 * 2);

  const size_t NEED = (size_t)194 * 1024 * 1024;
  bool big = ws_size >= NEED;

  conv4<<<2048, 256, 0, stream>>>(Wq, Wk, Wv, Wo, Wqb, Wkb, Wvb, Wob);
  pek<<<544, 256, 0, stream>>>(keype, peT);

  __bf16* obuf;
  if (big) {
    __bf16* qbf = (__bf16*)alloc((size_t)8 * 512 * 1024 * 2);
    __bf16* kbf = (__bf16*)alloc((size_t)8 * 2560 * 1024 * 2);
    __bf16* vbf = (__bf16*)alloc((size_t)8 * 2560 * 1024 * 2);
    obuf = qbf;   // qbf dead after projk_c; obuf born at attnk
    convin<<<22528, 256, 0, stream>>>(query, key, value, qbf, kbf, vbf);
    projk_c<<<2816, 256, 0, stream>>>(qbf, kbf, vbf, Wqb, Wkb, Wvb, qws, kws, vtws);
  } else {
    obuf = (__bf16*)alloc((size_t)4096 * 1024 * 2);
    projk_f32<<<2816, 256, 0, stream>>>(query, key, value, Wqb, Wkb, Wvb,
                                        qws, kws, vtws);
  }

  attnk<<<4096, 64, 0, stream>>>(qws, kws, vtws, peT, obuf);
  gemm_out<<<256, 256, 0, stream>>>(obuf, Wob, out);
}

// Round 13
// 381.979 us; speedup vs baseline: 1.4930x; 1.4930x over previous
//
#include <hip/hip_runtime.h>
#include <hip/hip_bf16.h>
#include <stdint.h>

// ---------------------------------------------------------------------------
// MultiHeadSeqAttention (Transformer-XL style sliding-window rel-pos attention)
// HID=1024, NHEADS=16, HEAD=64, MEM=512, LIM=2048, B=8
// logit(m,n) = q[m]·k[n] + q[m]·pe[:,n-m],  n-m in [0,2048)
// ---------------------------------------------------------------------------

typedef __attribute__((ext_vector_type(8))) __bf16 bfrag;   // MFMA A/B operand
typedef __attribute__((ext_vector_type(4))) float f4;       // MFMA C/D

#define DEVFN static __device__ __forceinline__

DEVFN void glds16(const void* g, void* l) {
  __builtin_amdgcn_global_load_lds((const __attribute__((address_space(1))) void*)g,
                                   (__attribute__((address_space(3))) void*)l, 16, 0, 0);
}

DEVFN bfrag cvt8(const float* p) {
  f4 a = *(const f4*)p;
  f4 b = *(const f4*)(p + 4);
  bfrag v;
  v[0] = (__bf16)a.x; v[1] = (__bf16)a.y; v[2] = (__bf16)a.z; v[3] = (__bf16)a.w;
  v[4] = (__bf16)b.x; v[5] = (__bf16)b.y; v[6] = (__bf16)b.z; v[7] = (__bf16)b.w;
  return v;
}

// ------------------ fp32 -> bf16 convert, 4 weights in one launch ----------
__global__ __launch_bounds__(256) void conv4(const float* __restrict__ a0, const float* __restrict__ a1,
                                             const float* __restrict__ a2, const float* __restrict__ a3,
                                             __bf16* __restrict__ d0, __bf16* __restrict__ d1,
                                             __bf16* __restrict__ d2, __bf16* __restrict__ d3) {
  int bx = blockIdx.x;
  int sel = bx >> 9;
  const float* s = sel == 0 ? a0 : sel == 1 ? a1 : sel == 2 ? a2 : a3;
  __bf16* d = sel == 0 ? d0 : sel == 1 ? d1 : sel == 2 ? d2 : d3;
  int i = ((bx & 511) * 256 + (int)threadIdx.x) * 8;   // 512*256*8 = 1M exactly
  *(bfrag*)(d + i) = cvt8(s + i);
}

// ------------------ fp32 -> bf16 convert for q/k/v inputs ------------------
__global__ __launch_bounds__(256) void convin(const float* __restrict__ q, const float* __restrict__ k,
                                              const float* __restrict__ v,
                                              __bf16* __restrict__ qd, __bf16* __restrict__ kd,
                                              __bf16* __restrict__ vd) {
  int bx = blockIdx.x;
  const float* s; __bf16* d; int lb;
  if (bx < 2048)       { s = q; d = qd; lb = bx; }
  else if (bx < 12288) { s = k; d = kd; lb = bx - 2048; }
  else                 { s = v; d = vd; lb = bx - 12288; }
  int i = (lb * 256 + (int)threadIdx.x) * 8;
  *(bfrag*)(d + i) = cvt8(s + i);
}

// ---------------- transposed + zero-padded positional table ----------------
__global__ __launch_bounds__(256) void pek(const float* __restrict__ pe,
                                           __bf16* __restrict__ peT) {
  int i = blockIdx.x * 256 + threadIdx.x;   // grid covers 64*2048 + 128*64 exactly
  if (i < 64 * 2048) {
    int d = i >> 11, l = i & 2047;
    peT[(size_t)(l + 64) * 64 + d] = (__bf16)pe[i];
  } else {
    int zi = i - 64 * 2048;
    int row = zi >> 6, dd = zi & 63;
    int r = row < 64 ? row : (2112 + row - 64);
    peT[(size_t)r * 64 + dd] = (__bf16)0.f;
  }
}

// ---------------------------------------------------------------------------
// core16: 128x128 tile, BK=64, 16 K-steps, counted-vmcnt pipeline (R5 win).
// A (HBM) double-buffered; B (L2-hot weights) single-buffered. vmcnt(4)
// leaves the next A-tile's 4 loads in flight across the barrier.
// ---------------------------------------------------------------------------
DEVFN bfrag rdfrag(const __bf16* L, int row, int kc, int g) {
  return *(const bfrag*)&L[row * 64 + (((g + 4 * kc) ^ (row & 7)) << 3)];
}

DEVFN void core16(const __bf16* __restrict__ A, const __bf16* __restrict__ B,
                  __bf16* AL, __bf16* BL, f4 (&acc)[4][4],
                  int tid, int wr, int wc, int g, int cl) {
  auto stageA = [&](int s, int k0) {
#pragma unroll
    for (int j = 0; j < 4; ++j) {
      int slot = j * 256 + tid;
      int row = slot >> 3, ch = slot & 7;
      glds16(A + (size_t)row * 1024 + k0 + ((ch ^ (row & 7)) << 3),
             &AL[s * 8192 + (slot << 3)]);
    }
  };
  auto stageB = [&](int k0) {
#pragma unroll
    for (int j = 0; j < 4; ++j) {
      int slot = j * 256 + tid;
      int row = slot >> 3, ch = slot & 7;
      glds16(B + (size_t)row * 1024 + k0 + ((ch ^ (row & 7)) << 3),
             &BL[slot << 3]);
    }
  };

  stageA(0, 0);
  for (int kt = 0; kt < 16; ++kt) {
    const int s = kt & 1;
    stageB(kt * 64);
    if (kt < 15) {
      stageA(s ^ 1, (kt + 1) * 64);
      asm volatile("s_waitcnt vmcnt(4)" ::: "memory");
    } else {
      asm volatile("s_waitcnt vmcnt(0)" ::: "memory");
    }
    __builtin_amdgcn_s_barrier();
    const __bf16* As = &AL[s * 8192];
#pragma unroll
    for (int kc = 0; kc < 2; ++kc) {
      bfrag af[4], bf[4];
#pragma unroll
      for (int i = 0; i < 4; ++i) {
        af[i] = rdfrag(As, 64 * wr + 16 * i + cl, kc, g);
        bf[i] = rdfrag(BL, 64 * wc + 16 * i + cl, kc, g);
      }
      __builtin_amdgcn_s_setprio(1);
#pragma unroll
      for (int am = 0; am < 4; ++am)
#pragma unroll
        for (int bn = 0; bn < 4; ++bn)
          acc[am][bn] =
              __builtin_amdgcn_mfma_f32_16x16x32_bf16(af[am], bf[bn], acc[am][bn], 0, 0, 0);
      __builtin_amdgcn_s_setprio(0);
    }
    __builtin_amdgcn_s_barrier();
  }
}

// ---------------- fused q/k/v projection: C = A @ W^T, heads layout --------
__global__ __launch_bounds__(256) void projk_c(const __bf16* __restrict__ Aq, const __bf16* __restrict__ Ak,
                                               const __bf16* __restrict__ Av,
                                               const __bf16* __restrict__ Wqb, const __bf16* __restrict__ Wkb,
                                               const __bf16* __restrict__ Wvb,
                                               __bf16* __restrict__ qws, __bf16* __restrict__ kws,
                                               __bf16* __restrict__ vtws) {
  __shared__ alignas(16) __bf16 AL[2 * 128 * 64];   // 32 KiB (A dbuf)
  __shared__ alignas(16) __bf16 BL[128 * 64];       // 16 KiB (B single)
  int bx = blockIdx.x;
  const __bf16* A; const __bf16* B; __bf16* C; int nb, lb, rpb, trans;
  if (bx < 256)       { A = Aq; B = Wqb; C = qws;  lb = bx;        nb = 256;  rpb = 4;  trans = 0; }
  else if (bx < 1536) { A = Ak; B = Wkb; C = kws;  lb = bx - 256;  nb = 1280; rpb = 20; trans = 0; }
  else                { A = Av; B = Wvb; C = vtws; lb = bx - 1536; nb = 1280; rpb = 20; trans = 1; }

  const int tid = threadIdx.x;
  const int lane = tid & 63, wv = tid >> 6;
  const int wr = wv >> 1, wc = wv & 1;
  const int g = lane >> 4, cl = lane & 15;

  int v = (lb & 7) * (nb >> 3) + (lb >> 3);   // XCD-aware swizzle (nb % 8 == 0)
  const int trow = v >> 3;
  const int r0 = trow * 128, c0 = (v & 7) * 128;

  f4 acc[4][4] = {};
  core16(A + (size_t)r0 * 1024, B + (size_t)c0 * 1024, AL, BL, acc,
         tid, wr, wc, g, cl);

  int Sseq = rpb << 7;
  int b = trow / rpb;
  int sbase = r0 - b * Sseq;
#pragma unroll
  for (int am = 0; am < 4; ++am)
#pragma unroll
    for (int bn = 0; bn < 4; ++bn) {
      int jg = c0 + 64 * wc + 16 * bn + cl;
      int h = jg >> 6, d = jg & 63;
#pragma unroll
      for (int r = 0; r < 4; ++r) {
        int s = sbase + 64 * wr + 16 * am + 4 * g + r;
        size_t dst = trans ? ((size_t)(b * 16 + h) * 64 + d) * 2560 + s
                           : ((size_t)(b * 16 + h) * Sseq + s) * 64 + d;
        C[dst] = (__bf16)acc[am][bn][r];
      }
    }
}

// ------------------------- fp32 A reg-staging (fallback) -------------------
DEVFN void stageA_row(const float* ap, __bf16* lds, int arow, int ahalf) {
  const f4* p = (const f4*)ap;
#pragma unroll
  for (int q = 0; q < 4; ++q) {
    f4 a = p[2 * q], b = p[2 * q + 1];
    bfrag v;
    v[0] = (__bf16)a.x; v[1] = (__bf16)a.y; v[2] = (__bf16)a.z; v[3] = (__bf16)a.w;
    v[4] = (__bf16)b.x; v[5] = (__bf16)b.y; v[6] = (__bf16)b.z; v[7] = (__bf16)b.w;
    int ch = (4 * ahalf + q) ^ (arow & 7);
    *(bfrag*)&lds[arow * 64 + ch * 8] = v;
  }
}

// ---------------- fallback fused q/k/v projection (fp32 A) -----------------
__global__ __launch_bounds__(256) void projk_f32(const float* __restrict__ Aq, const float* __restrict__ Ak,
                                                 const float* __restrict__ Av,
                                                 const __bf16* __restrict__ Wqb, const __bf16* __restrict__ Wkb,
                                                 const __bf16* __restrict__ Wvb,
                                                 __bf16* __restrict__ qws, __bf16* __restrict__ kws,
                                                 __bf16* __restrict__ vtws) {
  __shared__ alignas(16) __bf16 Alds[128 * 64];
  __shared__ alignas(16) __bf16 Blds[128 * 64];
  int bx = blockIdx.x;
  const float* A; const __bf16* B; __bf16* C; int nb, lb, rpb, trans;
  if (bx < 256)       { A = Aq; B = Wqb; C = qws;  lb = bx;        nb = 256;  rpb = 4;  trans = 0; }
  else if (bx < 1536) { A = Ak; B = Wkb; C = kws;  lb = bx - 256;  nb = 1280; rpb = 20; trans = 0; }
  else                { A = Av; B = Wvb; C = vtws; lb = bx - 1536; nb = 1280; rpb = 20; trans = 1; }

  const int tid = threadIdx.x;
  const int lane = tid & 63, wv = tid >> 6;
  const int wr = wv >> 1, wc = wv & 1;
  const int g = lane >> 4, cl = lane & 15;

  int v = (lb & 7) * (nb >> 3) + (lb >> 3);
  const int trow = v >> 3;
  const int r0 = trow * 128, c0 = (v & 7) * 128;

  f4 acc[4][4] = {};

  for (int k0 = 0; k0 < 1024; k0 += 64) {
    __syncthreads();
#pragma unroll
    for (int i = 0; i < 4; ++i) {
      int slot = tid + 256 * i;
      int row = slot >> 3, ch = slot & 7;
      glds16(B + (size_t)(c0 + row) * 1024 + k0 + ((ch ^ (row & 7)) << 3),
             &Blds[slot << 3]);
    }
    stageA_row(A + (size_t)(r0 + (tid >> 1)) * 1024 + k0 + (tid & 1) * 32,
               Alds, tid >> 1, tid & 1);
    __syncthreads();
#pragma unroll
    for (int kc = 0; kc < 2; ++kc) {
      bfrag af[4], bfv[4];
#pragma unroll
      for (int i = 0; i < 4; ++i) {
        int rA = 64 * wr + 16 * i + cl;
        af[i] = *(const bfrag*)&Alds[rA * 64 + (((g + 4 * kc) ^ (rA & 7)) << 3)];
        int rB = 64 * wc + 16 * i + cl;
        bfv[i] = *(const bfrag*)&Blds[rB * 64 + (((g + 4 * kc) ^ (rB & 7)) << 3)];
      }
#pragma unroll
      for (int am = 0; am < 4; ++am)
#pragma unroll
        for (int bn = 0; bn < 4; ++bn)
          acc[am][bn] =
              __builtin_amdgcn_mfma_f32_16x16x32_bf16(af[am], bfv[bn], acc[am][bn], 0, 0, 0);
    }
  }

  int Sseq = rpb << 7;
  int b = trow / rpb;
  int sbase = r0 - b * Sseq;
#pragma unroll
  for (int am = 0; am < 4; ++am)
#pragma unroll
    for (int bn = 0; bn < 4; ++bn) {
      int jg = c0 + 64 * wc + 16 * bn + cl;
      int h = jg >> 6, d = jg & 63;
#pragma unroll
      for (int r = 0; r < 4; ++r) {
        int s = sbase + 64 * wr + 16 * am + 4 * g + r;
        size_t dst = trans ? ((size_t)(b * 16 + h) * 64 + d) * 2560 + s
                           : ((size_t)(b * 16 + h) * Sseq + s) * 64 + d;
        C[dst] = (__bf16)acc[am][bn][r];
      }
    }
}

// -------------------------- output projection (f32 out) --------------------
__global__ __launch_bounds__(256) void gemm_out(const __bf16* __restrict__ A,
                                                const __bf16* __restrict__ B,
                                                float* __restrict__ C) {
  __shared__ alignas(16) __bf16 AL[2 * 128 * 64];
  __shared__ alignas(16) __bf16 BL[128 * 64];
  const int tid = threadIdx.x;
  const int lane = tid & 63, wv = tid >> 6;
  const int wr = wv >> 1, wc = wv & 1;
  const int g = lane >> 4, cl = lane & 15;

  int bx = blockIdx.x;
  int v = (bx & 7) * 32 + (bx >> 3);
  const int r0 = (v >> 3) * 128, c0 = (v & 7) * 128;

  f4 acc[4][4] = {};
  core16(A + (size_t)r0 * 1024, B + (size_t)c0 * 1024, AL, BL, acc,
         tid, wr, wc, g, cl);

#pragma unroll
  for (int am = 0; am < 4; ++am)
#pragma unroll
    for (int bn = 0; bn < 4; ++bn)
#pragma unroll
      for (int r = 0; r < 4; ++r) {
        int rg = r0 + 64 * wr + 16 * am + 4 * g + r;
        int jg = c0 + 64 * wc + 16 * bn + cl;
        C[(size_t)rg * 1024 + jg] = acc[am][bn][r];
      }
}

// --------------------------- fused window attention ------------------------
// EXACT R5-verified attnk (best measured: 172 us, passed replay validation):
// one block per (bh, 64-row q tile), 4 waves, fixed-max softmax,
// LDS 40960 B = 4 blocks/CU. R12's ring swizzle removed (caused
// nondeterministic post-timing divergence; mechanism unresolved -> reverted).
#define SCL 0.18033688011112042f   // (1/8) * log2(e)
#define FMX 20.0f

__global__ __launch_bounds__(256) void attnk(const __bf16* __restrict__ qws,
                                             const __bf16* __restrict__ kws,
                                             const __bf16* __restrict__ vtws,
                                             const __bf16* __restrict__ pews,
                                             __bf16* __restrict__ obuf) {
  __shared__ alignas(16) __bf16 Ks[64 * 64];    // K tile [n][d], chunk-XOR
  __shared__ alignas(16) __bf16 QVs[64 * 64];   // Q (prologue) then V^T tiles
  __shared__ alignas(16) __bf16 PPs[64 * 64];   // PE rows, then P (post-barrier)
  __shared__ alignas(16) __bf16 Pbs[64 * 128];  // pos ring: [jm][l & 127]

  int bx = blockIdx.x;
  int vv = (bx & 7) * 128 + (bx >> 3);          // XCD swizzle
  int bh = vv >> 3, mt = vv & 7;
  int m0 = mt * 64;
  const __bf16* qb = qws + (size_t)bh * 512 * 64;
  const __bf16* kb = kws + (size_t)bh * 2560 * 64;
  const __bf16* vb = vtws + (size_t)bh * 64 * 2560;

  const int tid = threadIdx.x;
  const int lane = tid & 63, w = tid >> 6;
  const int g = lane >> 4, cl = lane & 15;

  // stage Q (chunk-XOR pre-swizzled source), hoist all A-frags
#pragma unroll
  for (int i = 0; i < 2; ++i) {
    int slot = tid + 256 * i;
    int row = slot >> 3, ch = slot & 7;
    glds16(qb + (size_t)(m0 + row) * 64 + ((ch ^ (row & 7)) << 3), &QVs[slot << 3]);
  }
  __syncthreads();
  bfrag qf_all[4][2];
#pragma unroll
  for (int rb = 0; rb < 4; ++rb) {
    int rq = 16 * rb + cl;
#pragma unroll
    for (int kc = 0; kc < 2; ++kc)
      qf_all[rb][kc] = *(const bfrag*)&QVs[rq * 64 + (((g + 4 * kc) ^ (rq & 7)) << 3)];
  }

  f4 o[4] = {};
  float lsum[4] = {};

  for (int t = 0; t < 33; ++t) {
    int n0 = m0 + 64 * t;
    __syncthreads();
    // stage K tile [n][d], V^T tile [d][n] (into QVs), new PE rows (into PPs)
#pragma unroll
    for (int i = 0; i < 2; ++i) {
      int slot = tid + 256 * i;
      int row = slot >> 3, ch = slot & 7;
      glds16(kb + (size_t)(n0 + row) * 64 + ((ch ^ (row & 7)) << 3), &Ks[slot << 3]);
      glds16(vb + (size_t)row * 2560 + n0 + ((ch ^ (row & 7)) << 3), &QVs[slot << 3]);
      glds16(pews + (size_t)(64 * (t + 1) + row) * 64 + ((ch ^ (row & 7)) << 3),
             &PPs[slot << 3]);
    }
    __syncthreads();

    // content scores: wave w owns rows 16w..16w+15, all 64 cols
    f4 sc[4] = {};
    __builtin_amdgcn_s_setprio(1);
#pragma unroll
    for (int kc = 0; kc < 2; ++kc)
#pragma unroll
      for (int cb = 0; cb < 4; ++cb) {
        int rk = 16 * cb + cl;
        bfrag kf = *(const bfrag*)&Ks[rk * 64 + (((g + 4 * kc) ^ (rk & 7)) << 3)];
        sc[cb] = __builtin_amdgcn_mfma_f32_16x16x32_bf16(qf_all[w][kc], kf, sc[cb], 0, 0, 0);
      }
    // positional band, new 64 cols (l = 64t + c2): col-split across waves
    f4 pbacc[4] = {};
#pragma unroll
    for (int kc = 0; kc < 2; ++kc) {
      int rp = 16 * w + cl;
      bfrag pf = *(const bfrag*)&PPs[rp * 64 + (((g + 4 * kc) ^ (rp & 7)) << 3)];
#pragma unroll
      for (int rb = 0; rb < 4; ++rb)
        pbacc[rb] = __builtin_amdgcn_mfma_f32_16x16x32_bf16(qf_all[rb][kc], pf, pbacc[rb], 0, 0, 0);
    }
    __builtin_amdgcn_s_setprio(0);
    {
      int half = (t & 1) << 6;
      int c2 = 16 * w + cl;
#pragma unroll
      for (int rb = 0; rb < 4; ++rb)
#pragma unroll
        for (int r = 0; r < 4; ++r)
          Pbs[(16 * rb + 4 * g + r) * 128 + half + c2] = (__bf16)pbacc[rb][r];
    }
    __syncthreads();   // Pbs written col-split, read row-split; PPs reads done

    // fixed-max softmax: no shuffles, no rescale; P overwrites PE in PPs
    bool edge = (t == 0) || (t == 32);
#pragma unroll
    for (int r = 0; r < 4; ++r) {
      int jm = 16 * w + 4 * g + r;
#pragma unroll
      for (int cb = 0; cb < 4; ++cb) {
        int jn = 16 * cb + cl;
        int l = 64 * t + jn - jm;
        float pv = (float)Pbs[jm * 128 + (l & 127)];
        float ex = fmaf(sc[cb][r] + pv, SCL, -FMX);
        if (edge) ex = ((unsigned)l < 2048u) ? ex : -1e30f;
        float p = __builtin_amdgcn_exp2f(ex);
        lsum[r] += p;
        PPs[jm * 64 + (((jn >> 3) ^ (jm & 7)) << 3) + (jn & 7)] = (__bf16)p;
      }
    }

    // O += P @ V  (P rows wave-private -> no barrier; V^T gives k-contig frags)
    __builtin_amdgcn_s_setprio(1);
#pragma unroll
    for (int kc = 0; kc < 2; ++kc) {
      int rp2 = 16 * w + cl;
      bfrag pa = *(const bfrag*)&PPs[rp2 * 64 + (((g + 4 * kc) ^ (rp2 & 7)) << 3)];
#pragma unroll
      for (int cb = 0; cb < 4; ++cb) {
        int rv = 16 * cb + cl;
        bfrag vf = *(const bfrag*)&QVs[rv * 64 + (((g + 4 * kc) ^ (rv & 7)) << 3)];
        o[cb] = __builtin_amdgcn_mfma_f32_16x16x32_bf16(pa, vf, o[cb], 0, 0, 0);
      }
    }
    __builtin_amdgcn_s_setprio(0);
  }

  // epilogue: reduce lsum over the 16 cl-lanes, normalize, write bf16
#pragma unroll
  for (int r = 0; r < 4; ++r)
#pragma unroll
    for (int off = 1; off < 16; off <<= 1) lsum[r] += __shfl_xor(lsum[r], off);

  int b = bh >> 4, h = bh & 15;
#pragma unroll
  for (int cb = 0; cb < 4; ++cb)
#pragma unroll
    for (int r = 0; r < 4; ++r) {
      int m = m0 + 16 * w + 4 * g + r;
      int d = 16 * cb + cl;
      obuf[((size_t)(b * 512 + m)) * 1024 + h * 64 + d] = (__bf16)(o[cb][r] / lsum[r]);
    }
}

// ---------------------------------------------------------------------------
extern "C" void kernel_launch(void* const* d_in, const int* in_sizes, int n_in,
                              void* d_out, int out_size, void* d_ws, size_t ws_size,
                              hipStream_t stream) {
  const float* query = (const float*)d_in[0];
  const float* key   = (const float*)d_in[1];
  const float* value = (const float*)d_in[2];
  const float* keype = (const float*)d_in[3];
  const float* Wq    = (const float*)d_in[4];
  const float* Wk    = (const float*)d_in[5];
  const float* Wv    = (const float*)d_in[6];
  const float* Wo    = (const float*)d_in[7];
  float* out = (float*)d_out;
  (void)in_sizes; (void)n_in; (void)out_size;

  char* ws = (char*)d_ws;
  size_t off = 0;
  auto alloc = [&](size_t bytes) {
    void* p = ws + off;
    off += (bytes + 255) & ~(size_t)255;
    return p;
  };
  __bf16* Wqb  = (__bf16*)alloc((size_t)1024 * 1024 * 2);
  __bf16* Wkb  = (__bf16*)alloc((size_t)1024 * 1024 * 2);
  __bf16* Wvb  = (__bf16*)alloc((size_t)1024 * 1024 * 2);
  __bf16* Wob  = (__bf16*)alloc((size_t)1024 * 1024 * 2);
  __bf16* peT  = (__bf16*)alloc((size_t)2176 * 64 * 2);
  __bf16* qws  = (__bf16*)alloc((size_t)128 * 512 * 64 * 2);
  __bf16* kws  = (__bf16*)alloc((size_t)128 * 2560 * 64 * 2);
  __bf16* vtws = (__bf16*)alloc((size_t)128 * 2560 * 64 * 2);

  const size_t NEED = (size_t)194 * 1024 * 1024;
  bool big = ws_size >= NEED;

  conv4<<<2048, 256, 0, stream>>>(Wq, Wk, Wv, Wo, Wqb, Wkb, Wvb, Wob);
  pek<<<544, 256, 0, stream>>>(keype, peT);

  __bf16* obuf;
  if (big) {
    __bf16* qbf = (__bf16*)alloc((size_t)8 * 512 * 1024 * 2);
    __bf16* kbf = (__bf16*)alloc((size_t)8 * 2560 * 1024 * 2);
    __bf16* vbf = (__bf16*)alloc((size_t)8 * 2560 * 1024 * 2);
    obuf = qbf;   // qbf dead after projk_c; obuf born at attnk
    convin<<<22528, 256, 0, stream>>>(query, key, value, qbf, kbf, vbf);
    projk_c<<<2816, 256, 0, stream>>>(qbf, kbf, vbf, Wqb, Wkb, Wvb, qws, kws, vtws);
  } else {
    obuf = (__bf16*)alloc((size_t)4096 * 1024 * 2);
    projk_f32<<<2816, 256, 0, stream>>>(query, key, value, Wqb, Wkb, Wvb,
                                        qws, kws, vtws);
  }

  attnk<<<1024, 256, 0, stream>>>(qws, kws, vtws, peT, obuf);
  gemm_out<<<256, 256, 0, stream>>>(obuf, Wob, out);
}